// Round 7
// baseline (510.356 us; speedup 1.0000x reference)
//
#include <hip/hip_runtime.h>
#include <math.h>

// Problem constants
#define NTOK 8192
#define MDIM 4096
#define NEXP 64
#define CAPACITY 128.0f

// Output layout (all fp32): [indices 8192][capacity 1][locations 8192][gates 8192][num_experts 1]
#define OFF_IDX  0
#define OFF_CAP  8192
#define OFF_LOC  8193
#define OFF_GATE 16385
#define OFF_NE   24577

// ws layout in 4-byte units: [done 16][cnt 8192][rk 8192][partials S*8192*64]
#define WS_DONE_OFF 0
#define WS_CNT_OFF  16
#define WS_RK_OFF   (16 + 8192)
#define WS_PART_OFF (16 + 16384)

// ---------------------------------------------------------------------------
// Gate partial GEMM, R7 ("lane = token; x via swizzled LDS; W via SMEM"):
//  - block = 4 waves = 64 tokens x 64 experts x K-slice. lane = token,
//    wave wv = expert group (16 experts). grid (128, S): S=8 -> 4096 waves.
//  - x: 64x64 chunk (16 KB) staged global->VGPR->LDS with XOR swizzle
//    [t][k4^(t&15)] (conflict-free write AND read), double-buffered, ONE
//    barrier per chunk. Each lane ds_read_b128's its own token row: 16
//    reads per wave-chunk (R4's broadcast scheme needed 256 -> LDS-bound).
//  - W: wave-uniform expert rows -> s_load_dwordx16 stream into SGPR
//    ping-pong (2 x 32, fully unrolled so no copies); prefetch of step n+1
//    issued BEFORE step n's FMA block so the coarse lgkmcnt(0) drain
//    overlaps 64 FMA cycles.
//  - acc: 2 chains per expert (A/B) for v_fma latency; deterministic k order.
// ---------------------------------------------------------------------------
template<int S>
__global__ __launch_bounds__(256, 4) void gate_partial(
    const float* __restrict__ x,
    const float* __restrict__ W,
    float* __restrict__ part,
    int* __restrict__ done)
{
    constexpr int KS = MDIM / S;     // K per slice
    constexpr int NC = KS / 64;      // 64-K chunks per slice
    __shared__ float4 xb[2][64 * 16];   // 2 x 16 KB, [t][p] p = k4 ^ (t&15)

    const int tid   = threadIdx.x;
    const int lane  = tid & 63;                                  // token
    const int wv    = __builtin_amdgcn_readfirstlane(tid >> 6);  // expert grp
    const int tok0  = blockIdx.x * 64;
    const int slice = blockIdx.y;
    const int k0    = slice * KS;
    const int ebase = wv * 16;

    if (blockIdx.x == 0 && slice == 0 && tid == 0) *done = 0;

    const float4* __restrict__ x4 = (const float4*)x;

    // staging pattern: unit j covers ii = tid + j*256 -> (trel, k4)
    int trelJ[4], k4J[4], ldsw[4];
    #pragma unroll
    for (int j = 0; j < 4; ++j) {
        int ii = tid + j * 256;
        trelJ[j] = ii >> 4;
        k4J[j]   = ii & 15;
        ldsw[j]  = trelJ[j] * 16 + (k4J[j] ^ (trelJ[j] & 15));
    }

    float accA[16], accB[16];
    #pragma unroll
    for (int e = 0; e < 16; ++e) { accA[e] = 0.f; accB[e] = 0.f; }

    float4 sreg[4];

    // prologue: stage chunk 0 into buffer 0
    #pragma unroll
    for (int j = 0; j < 4; ++j)
        sreg[j] = x4[(size_t)(tok0 + trelJ[j]) * (MDIM / 4) + (k0 >> 2) + k4J[j]];
    #pragma unroll
    for (int j = 0; j < 4; ++j) xb[0][ldsw[j]] = sreg[j];
    __syncthreads();

    for (int c = 0; c < NC; ++c) {
        const int cur = c & 1;

        // issue global loads for chunk c+1 (consumed after compute)
        if (c + 1 < NC) {
            #pragma unroll
            for (int j = 0; j < 4; ++j)
                sreg[j] = x4[(size_t)(tok0 + trelJ[j]) * (MDIM / 4)
                             + (k0 >> 2) + (c + 1) * 16 + k4J[j]];
        }

        // ---- compute on xb[cur]: 16 experts x 64 K
        {
            float wbuf2[2][32];   // SGPR ping-pong (scalar loads, uniform)
            const int kchunk = k0 + c * 64;

            // preload step 0 (h=0, e=0)
            {
                const float* __restrict__ wr = W + (size_t)ebase * MDIM + kchunk;
                #pragma unroll
                for (int i = 0; i < 32; ++i) wbuf2[0][i] = wr[i];
            }

            #pragma unroll
            for (int h = 0; h < 2; ++h) {
                float4 xr[8];
                #pragma unroll
                for (int r = 0; r < 8; ++r)
                    xr[r] = xb[cur][lane * 16 + ((h * 8 + r) ^ (lane & 15))];

                #pragma unroll
                for (int e = 0; e < 16; ++e) {
                    const int step = h * 16 + e;
                    const int pb   = step & 1;
                    if (step + 1 < 32) {   // prefetch next (h,e) W half-row
                        const int hn = (step + 1) >> 4;
                        const int en = (step + 1) & 15;
                        const float* __restrict__ wr =
                            W + (size_t)(ebase + en) * MDIM + kchunk + hn * 32;
                        #pragma unroll
                        for (int i = 0; i < 32; ++i) wbuf2[pb ^ 1][i] = wr[i];
                    }
                    float a = accA[e], b = accB[e];
                    #pragma unroll
                    for (int r = 0; r < 8; ++r) {
                        a = fmaf(xr[r].x, wbuf2[pb][r * 4 + 0], a);
                        b = fmaf(xr[r].y, wbuf2[pb][r * 4 + 1], b);
                        a = fmaf(xr[r].z, wbuf2[pb][r * 4 + 2], a);
                        b = fmaf(xr[r].w, wbuf2[pb][r * 4 + 3], b);
                    }
                    accA[e] = a; accB[e] = b;
                }
            }
        }

        // write staged chunk c+1 into the other buffer, then one barrier
        if (c + 1 < NC) {
            #pragma unroll
            for (int j = 0; j < 4; ++j) xb[cur ^ 1][ldsw[j]] = sreg[j];
        }
        __syncthreads();
    }

    // partials: token = lane, experts ebase..ebase+15 (contiguous 64 B)
    float4* __restrict__ pp =
        (float4*)(part + ((size_t)slice * NTOK + tok0 + lane) * 64 + ebase);
    #pragma unroll
    for (int e4 = 0; e4 < 4; ++e4)
        pp[e4] = make_float4(accA[e4*4+0] + accB[e4*4+0],
                             accA[e4*4+1] + accB[e4*4+1],
                             accA[e4*4+2] + accB[e4*4+2],
                             accA[e4*4+3] + accB[e4*4+3]);
}

// ---------------------------------------------------------------------------
// Fused tail (proven in R5/R6): reduce partials + argmax/softmax + histogram/
// rank; last block (device-scope ticket) scans and writes locations.
// ---------------------------------------------------------------------------
template<int S>
__global__ __launch_bounds__(256) void reduce_all(
    const float* __restrict__ part,
    float* __restrict__ out,
    int* __restrict__ cnt,
    int* __restrict__ rk,
    int* __restrict__ done)
{
    __shared__ int eidx[64];
    __shared__ int lcnt[128 * 64];   // 32 KB, used by the winning block
    __shared__ int wtot[4 * 64];
    __shared__ int tick_s;

    const int tid  = threadIdx.x;
    const int lane = tid & 63;
    const int wv   = tid >> 6;
    const int tok0 = blockIdx.x * 64;
    const int trel = wv * 16 + (lane >> 2);
    const int tok  = tok0 + trel;
    const int q    = lane & 3;

    const float4* __restrict__ p4 = (const float4*)part;

    // phase 1: deterministic slice-ascending reduce, 16 experts/lane
    float4 a[4];
    #pragma unroll
    for (int r = 0; r < 4; ++r) a[r] = make_float4(0.f, 0.f, 0.f, 0.f);
    for (int s = 0; s < S; ++s) {
        #pragma unroll
        for (int r = 0; r < 4; ++r) {
            float4 v = p4[((size_t)s * NTOK + tok) * 16 + q * 4 + r];
            a[r].x += v.x; a[r].y += v.y; a[r].z += v.z; a[r].w += v.w;
        }
    }

    float vals[16];
    #pragma unroll
    for (int r = 0; r < 4; ++r) {
        vals[r * 4 + 0] = a[r].x; vals[r * 4 + 1] = a[r].y;
        vals[r * 4 + 2] = a[r].z; vals[r * 4 + 3] = a[r].w;
    }

    float bm = vals[0];
    int   be = q * 16;
    #pragma unroll
    for (int j = 1; j < 16; ++j)
        if (vals[j] > bm) { bm = vals[j]; be = q * 16 + j; }
    #pragma unroll
    for (int off = 1; off <= 2; off <<= 1) {
        float om = __shfl_xor(bm, off, 64);
        int   oe = __shfl_xor(be, off, 64);
        if (om > bm || (om == bm && oe < be)) { bm = om; be = oe; }
    }

    float es = 0.f;
    #pragma unroll
    for (int j = 0; j < 16; ++j) es += expf(vals[j] - bm);
    #pragma unroll
    for (int off = 1; off <= 2; off <<= 1)
        es += __shfl_xor(es, off, 64);

    if (q == 0) {
        out[OFF_IDX  + tok] = (float)be;
        out[OFF_GATE + tok] = 1.0f / es;
        eidx[trel] = be;
    }
    __syncthreads();

    // phase 2: per-chunk histogram + in-chunk ranks (wave 0)
    if (tid < 64) {
        const int e = eidx[tid];
        const unsigned long long lt =
            (tid == 0) ? 0ull : ((~0ull) >> (64 - tid));
        unsigned long long mymask = 0;
        int myrk = 0;
        for (int ee = 0; ee < 64; ++ee) {
            unsigned long long mb = __ballot(e == ee);
            if (tid == ee) mymask = mb;
            if (e == ee)   myrk   = (int)__popcll(mb & lt);
        }
        cnt[blockIdx.x * 64 + tid] = (int)__popcll(mymask);
        rk[tok0 + tid] = myrk;
    }
    if (tid == 0 && blockIdx.x == 0) {
        out[OFF_CAP] = CAPACITY;
        out[OFF_NE]  = (float)NEXP;
    }

    // phase 3: last block scans + finalizes locations
    __threadfence();
    __syncthreads();
    if (tid == 0) tick_s = atomicAdd(done, 1);
    __syncthreads();
    if (tick_s == 127) {
        __threadfence();

        for (int j = 0; j < 32; ++j)
            lcnt[j * 256 + tid] = cnt[j * 256 + tid];
        __syncthreads();

        int sum = 0;
        for (int j = 0; j < 32; ++j) sum += lcnt[(wv * 32 + j) * 64 + lane];
        wtot[wv * 64 + lane] = sum;
        __syncthreads();

        if (tid < 64) {
            int run = 0;
            #pragma unroll
            for (int w2 = 0; w2 < 4; ++w2) {
                int t = wtot[w2 * 64 + tid];
                wtot[w2 * 64 + tid] = run;
                run += t;
            }
        }
        __syncthreads();

        int run = wtot[wv * 64 + lane];
        for (int j = 0; j < 32; ++j) {
            int c = (wv * 32 + j) * 64 + lane;
            int v = lcnt[c];
            lcnt[c] = run;
            run += v;
        }
        __syncthreads();

        for (int j = 0; j < 32; ++j) {
            int s = j * 256 + tid;
            int e = (int)out[OFF_IDX + s];
            out[OFF_LOC + s] = (float)(lcnt[(s >> 6) * 64 + e] + rk[s]);
        }
    }
}

extern "C" void kernel_launch(void* const* d_in, const int* in_sizes, int n_in,
                              void* d_out, int out_size, void* d_ws, size_t ws_size,
                              hipStream_t stream)
{
    const float* x = (const float*)d_in[0];   // [8192, 4096] fp32
    const float* W = (const float*)d_in[1];   // [64, 4096] fp32
    float* out = (float*)d_out;               // 24578 fp32

    int*   done = (int*)d_ws + WS_DONE_OFF;
    int*   cnt  = (int*)d_ws + WS_CNT_OFF;
    int*   rk   = (int*)d_ws + WS_RK_OFF;
    float* part = (float*)d_ws + WS_PART_OFF;

    const size_t base = (size_t)WS_PART_OFF * 4;
    const size_t per_slice = (size_t)NTOK * 64 * 4;   // 2 MB

    if (ws_size >= base + 8 * per_slice) {
        gate_partial<8><<<dim3(128, 8), 256, 0, stream>>>(x, W, part, done);
        reduce_all<8><<<128, 256, 0, stream>>>(part, out, cnt, rk, done);
    } else {
        gate_partial<4><<<dim3(128, 4), 256, 0, stream>>>(x, W, part, done);
        reduce_all<4><<<128, 256, 0, stream>>>(part, out, cnt, rk, done);
    }
}